// Round 3
// baseline (23.258 us; speedup 1.0000x reference)
//
#include <hip/hip_runtime.h>

// CRF-RNN 1-D message passing — register-resident q/weights, LDS-staged inputs.
// B=16, N=100000, K=11 (HALF=5), 5 Jacobi iterations.
// Thread owns G=8 consecutive positions. Weights computed once from LDS-staged
// features (padded float4, XOR-swizzled segs -> conflict-free ds_read_b128),
// normalized into VGPRs; per-iteration only a 5-wide q halo goes through LDS.

constexpr int BLK   = 64;            // one wave per block
constexpr int G     = 8;             // positions per thread
constexpr int E     = BLK * G;       // 512 ext positions per block
constexpr int HL    = 28;            // halo each side (>=25, mult of 4)
constexpr int C     = E - 2 * HL;    // 456 outputs per block
constexpr int NITER = 5;
constexpr int OF    = 8;             // feature staging extra margin
constexpr int FE    = E + 2 * OF;    // 528 staged feature positions
constexpr int NSEGQ = E / 4;         // 128 q segments
constexpr float EPS = 1e-8f;

__device__ __forceinline__ float frcp(float x) { return __builtin_amdgcn_rcpf(x); }
__device__ __forceinline__ float sigm(float x) { return frcp(1.0f + __expf(-x)); }
__device__ __forceinline__ int   swzseg(int s) { return s ^ ((s >> 3) & 7); }
__device__ __forceinline__ int   swzd(int d)   { int s = d >> 2; return (swzseg(s) << 2) | (d & 3); }

__global__ __launch_bounds__(BLK, 3) void crf_kernel(
    const float* __restrict__ logits, const float* __restrict__ p,
    float* __restrict__ out, int N, int chunks_per_b)
{
  __shared__ float4 s_f4[FE];    // feature pos+OF, padded float4, seg-swizzled
  __shared__ float  s_lg[E];     // logits, dword-swizzled
  __shared__ float4 s_q4[NSEGQ]; // q halo exchange, seg-swizzled

  const int b     = blockIdx.x / chunks_per_b;
  const int chunk = blockIdx.x % chunks_per_b;
  const int s0    = chunk * C - HL;       // global index of ext position 0
  const int t     = threadIdx.x;
  const int base  = G * t;                // ext index of own pos 0
  const int gb    = s0 + base;            // global index of own pos 0
  const float* lg = logits + (size_t)b * N;
  const float* pp = p + (size_t)b * N * 3;

  // ---- stage features: dense scalar loads -> padded swizzled float4 ----
  #pragma unroll
  for (int jp = 0; jp < 9; ++jp) {
    int idx = 64 * jp + t;               // staged ext-pos + OF
    if (idx < FE) {
      int g  = s0 + idx - OF;
      int gc = min(max(g, 0), N - 1);
      const float* src = pp + 3 * (size_t)gc;
      s_f4[swzseg(idx)] = make_float4(src[0], src[1], src[2], 0.0f);
    }
  }
  // ---- stage logits: dense scalar loads, swizzled dwords ----
  #pragma unroll
  for (int jl = 0; jl < 8; ++jl) {
    int idx = 64 * jl + t;
    int g   = s0 + idx;
    int gc  = min(max(g, 0), N - 1);
    s_lg[swzd(idx)] = lg[gc];
  }
  __syncthreads();

  // ---- weights via 6-entry rolling window of ds_read_b128 ----
  float wr[G][5], wl[G][5];
  float4 win[6];
  #pragma unroll
  for (int j = 0; j < 5; ++j) win[j] = s_f4[swzseg(base - 5 + j + OF)];
  #pragma unroll
  for (int i = 0; i < 13; ++i) {
    win[(i + 5) % 6] = s_f4[swzseg(base + i + OF)];   // pos = base-5+(i+5)
    const float4 a = win[i % 6];                       // pos_i = base-5+i
    const int g = gb + i - 5;
    #pragma unroll
    for (int d = 0; d < 5; ++d) {
      const float4 bb = win[(i + d + 1) % 6];
      float d0 = a.x - bb.x, d1 = a.y - bb.y, d2 = a.z - bb.z;
      float ex = __expf(-0.5f * (d0 * d0 + d1 * d1 + d2 * d2));
      bool valid = (g >= 0) && (g + d + 1 < N);
      ex = valid ? ex : 0.0f;
      if (i >= 5) wr[i - 5][d] = ex;                   // right-weight of pos_i
      const int kl = i + d - 4;                        // left-weight of pos_i+d+1
      if (kl >= 0 && kl < G) wl[kl][d] = ex;
    }
  }
  // normalize
  #pragma unroll
  for (int k = 0; k < G; ++k) {
    float ws = EPS;
    #pragma unroll
    for (int d = 0; d < 5; ++d) ws += wr[k][d] + wl[k][d];
    float inv = frcp(ws);
    #pragma unroll
    for (int d = 0; d < 5; ++d) { wr[k][d] *= inv; wl[k][d] *= inv; }
  }

  // ---- unary + q0 ----
  float un[G], q[G];
  {
    const float4* lg4 = (const float4*)s_lg;
    float4 u0 = lg4[swzseg(2 * t)];
    float4 u1 = lg4[swzseg(2 * t + 1)];
    un[0] = u0.x; un[1] = u0.y; un[2] = u0.z; un[3] = u0.w;
    un[4] = u1.x; un[5] = u1.y; un[6] = u1.z; un[7] = u1.w;
    #pragma unroll
    for (int k = 0; k < G; ++k) q[k] = sigm(un[k]);
  }

  // ---- swizzled q-halo addresses (loop-invariant) ----
  const int sgA  = swzseg(2 * t);
  const int sgB  = swzseg(2 * t + 1);
  const int sgL0 = swzseg(max(2 * t - 2, 0));
  const int sgL1 = swzseg(max(2 * t - 1, 0));
  const int sgR0 = swzseg(min(2 * t + 2, NSEGQ - 1));
  const int sgR1 = swzseg(min(2 * t + 3, NSEGQ - 1));

  s_q4[sgA] = make_float4(q[0], q[1], q[2], q[3]);
  s_q4[sgB] = make_float4(q[4], q[5], q[6], q[7]);
  __syncthreads();

  // ---- 5 Jacobi iterations; only halo via LDS ----
  #pragma unroll
  for (int it = 0; it < NITER; ++it) {
    float4 L0 = s_q4[sgL0];
    float4 L1 = s_q4[sgL1];
    float4 R0 = s_q4[sgR0];
    float4 R1 = s_q4[sgR1];
    float qx[18];   // q at ext position base + j - 5
    qx[0] = L0.w; qx[1] = L1.x; qx[2] = L1.y; qx[3] = L1.z; qx[4] = L1.w;
    #pragma unroll
    for (int k = 0; k < G; ++k) qx[5 + k] = q[k];
    qx[13] = R0.x; qx[14] = R0.y; qx[15] = R0.z; qx[16] = R0.w; qx[17] = R1.x;

    #pragma unroll
    for (int k = 0; k < G; ++k) {
      float msg = 0.0f;
      #pragma unroll
      for (int d = 0; d < 5; ++d) {
        msg += wl[k][d] * qx[5 + k - d - 1];
        msg += wr[k][d] * qx[5 + k + d + 1];
      }
      q[k] = sigm(un[k] + msg);
    }

    if (it != NITER - 1) {
      __syncthreads();
      s_q4[sgA] = make_float4(q[0], q[1], q[2], q[3]);
      s_q4[sgB] = make_float4(q[4], q[5], q[6], q[7]);
      __syncthreads();
    }
  }

  // ---- vectorized aligned output stores ----
  // out region: e in [HL, E-HL), g = chunk*C + (e - HL), valid while g < N
  float* ob = out + (size_t)b * N;
  #pragma unroll
  for (int h = 0; h < 2; ++h) {
    const int e0 = base + 4 * h;
    if (e0 >= HL && e0 + 4 <= E - HL) {
      const int gidx = chunk * C + (e0 - HL);
      float4 v = make_float4(q[4 * h], q[4 * h + 1], q[4 * h + 2], q[4 * h + 3]);
      if (gidx + 3 < N) {
        *(float4*)(ob + gidx) = v;
      } else {
        #pragma unroll
        for (int j = 0; j < 4; ++j)
          if (gidx + j < N) ob[gidx + j] = (&v.x)[j];
      }
    }
  }
}

extern "C" void kernel_launch(void* const* d_in, const int* in_sizes, int n_in,
                              void* d_out, int out_size, void* d_ws, size_t ws_size,
                              hipStream_t stream) {
  const float* logits = (const float*)d_in[0];
  const float* p      = (const float*)d_in[1];
  float* out          = (float*)d_out;
  const int N = 100000;
  const int B = in_sizes[0] / N;                 // 16
  const int chunks_per_b = (N + C - 1) / C;      // 220
  dim3 grid(B * chunks_per_b), block(BLK);
  crf_kernel<<<grid, block, 0, stream>>>(logits, p, out, N, chunks_per_b);
}